// Round 1
// baseline (2637.795 us; speedup 1.0000x reference)
//
#include <hip/hip_runtime.h>
#include <hip/hip_bf16.h>

typedef __attribute__((ext_vector_type(4))) float f32x4;
typedef __attribute__((ext_vector_type(8))) __bf16 bf16x8;
typedef __attribute__((ext_vector_type(8))) unsigned short u16x8;

#define SCALE_ 0.17677669529663687f  /* 32^-0.5 */

// ---------- workspace layout (bytes) ----------
#define OFF_XN 0ull                  // bf16 [100352][384]  (windowed LN1 out; later y2)
#define OFF_AO 77070336ull           // bf16 [100352][384]  (attn out; later g1, y1)
#define OFF_WB 154140672ull          // bf16 weight copies (1,032,192 elems)

__device__ __forceinline__ __bf16 tobf(float f) {
  __hip_bfloat16 h = __float2bfloat16(f);
  return __builtin_bit_cast(__bf16, h);
}
__device__ __forceinline__ unsigned short f2u(float f) {
  return __builtin_bit_cast(unsigned short, __float2bfloat16(f));
}

// ---------- fp32 -> bf16 weight copy ----------
__global__ __launch_bounds__(256) void cvt_kernel(const float* __restrict__ src,
                                                  __hip_bfloat16* __restrict__ dst, int n) {
  int i = blockIdx.x * 256 + threadIdx.x;
  int stride = gridDim.x * 256;
  for (; i < n; i += stride) dst[i] = __float2bfloat16(src[i]);
}

// ---------- LayerNorm (one wave per token); WIN: write to rolled+windowed position ----------
template <bool WIN>
__global__ __launch_bounds__(256) void ln_kernel(const float* __restrict__ x,
                                                 const float* __restrict__ gm,
                                                 const float* __restrict__ bt,
                                                 __hip_bfloat16* __restrict__ out) {
  const int tok = blockIdx.x * 4 + (threadIdx.x >> 6);
  const int lane = threadIdx.x & 63;
  const float2* row = (const float2*)(x + (size_t)tok * 384);
  float2 v[3];
  v[0] = row[lane]; v[1] = row[lane + 64]; v[2] = row[lane + 128];
  float s = 0.f, sq = 0.f;
#pragma unroll
  for (int i = 0; i < 3; ++i) { s += v[i].x + v[i].y; sq += v[i].x * v[i].x + v[i].y * v[i].y; }
#pragma unroll
  for (int m = 1; m < 64; m <<= 1) { s += __shfl_xor(s, m, 64); sq += __shfl_xor(sq, m, 64); }
  const float mean = s * (1.f / 384.f);
  const float var = sq * (1.f / 384.f) - mean * mean;
  const float rstd = rsqrtf(var + 1e-5f);
  size_t dst;
  if constexpr (WIN) {
    int b = tok / 3136, l = tok - b * 3136;
    int i = l / 56, j = l - i * 56;
    int hp = i - 3; if (hp < 0) hp += 56;
    int wp = j - 3; if (wp < 0) wp += 56;
    int wi = (hp / 7) * 8 + wp / 7;
    int n = (hp % 7) * 7 + wp % 7;
    dst = (size_t)(b * 64 + wi) * 49 + n;
  } else {
    dst = (size_t)tok;
  }
  unsigned int* o = (unsigned int*)(out + dst * 384);
  const float2* G = (const float2*)gm;
  const float2* Bv = (const float2*)bt;
#pragma unroll
  for (int i = 0; i < 3; ++i) {
    int j = lane + 64 * i;
    float2 gv = G[j], bv = Bv[j];
    float a = (v[i].x - mean) * rstd * gv.x + bv.x;
    float b2 = (v[i].y - mean) * rstd * gv.y + bv.y;
    o[j] = (unsigned)f2u(a) | ((unsigned)f2u(b2) << 16);
  }
}

// ---------- fused window attention: one block per window, one wave = 3 heads ----------
__global__ __launch_bounds__(256) void attn_kernel(const __hip_bfloat16* __restrict__ xn,
                                                   const __hip_bfloat16* __restrict__ wq,
                                                   const float* __restrict__ qb,
                                                   const float* __restrict__ rpb,
                                                   __hip_bfloat16* __restrict__ ao) {
  const int win = blockIdx.x;        // 0..2047
  const int widx = win & 63;         // window-in-image
  const int lane = threadIdx.x & 63, wave = threadIdx.x >> 6;
  const int g = lane >> 4, r = lane & 15;

  __shared__ __align__(16) char lds_all[4][16384];
  // per-wave: q [64][40] @0 (5120B), k [64][40] @5120, vT [32][72] @10240 (4608B)
  // P [64][72] overlays q+k (9216B <= 10240B)
  __hip_bfloat16* q_l = (__hip_bfloat16*)&lds_all[wave][0];
  __hip_bfloat16* k_l = (__hip_bfloat16*)&lds_all[wave][5120];
  __hip_bfloat16* vT = (__hip_bfloat16*)&lds_all[wave][10240];
  __hip_bfloat16* P_l = (__hip_bfloat16*)&lds_all[wave][0];

  bf16x8 zf;
#pragma unroll
  for (int i = 0; i < 8; ++i) zf[i] = tobf(0.f);

  for (int hh = 0; hh < 3; ++hh) {
    const int head = hh * 4 + wave;
    {
      // ---- phase 1: qkv = win @ Wqkv^T ----
      f32x4 acc[3][4][2] = {};
      for (int kk = 0; kk < 12; ++kk) {
        const int kb = kk * 32 + g * 8;
        bf16x8 af[4];
#pragma unroll
        for (int mt = 0; mt < 4; ++mt) {
          int t = mt * 16 + r;
          af[mt] = (t < 49) ? *(const bf16x8*)(xn + ((size_t)win * 49 + t) * 384 + kb) : zf;
        }
#pragma unroll
        for (int s = 0; s < 3; ++s) {
          const int ob = s * 384 + head * 32;
#pragma unroll
          for (int nt = 0; nt < 2; ++nt) {
            bf16x8 bf = *(const bf16x8*)(wq + (size_t)(ob + nt * 16 + r) * 384 + kb);
#pragma unroll
            for (int mt = 0; mt < 4; ++mt)
              acc[s][mt][nt] =
                  __builtin_amdgcn_mfma_f32_16x16x32_bf16(af[mt], bf, acc[s][mt][nt], 0, 0, 0);
          }
        }
      }
#pragma unroll
      for (int mt = 0; mt < 4; ++mt)
#pragma unroll
        for (int nt = 0; nt < 2; ++nt)
#pragma unroll
          for (int j = 0; j < 4; ++j) {
            int row = mt * 16 + g * 4 + j;
            int col = nt * 16 + r;
            float qv = (acc[0][mt][nt][j] + qb[head * 32 + col]) * SCALE_;
            float kv = acc[1][mt][nt][j] + qb[384 + head * 32 + col];
            float vv = acc[2][mt][nt][j] + qb[768 + head * 32 + col];
            q_l[row * 40 + col] = __float2bfloat16(qv);
            k_l[row * 40 + col] = __float2bfloat16(kv);
            vT[col * 72 + row] = __float2bfloat16(vv);
          }
    }
    __syncthreads();
    // ---- phase 2: S = q @ k^T (K=32, one mfma per tile) ----
    f32x4 sA[4][4] = {};
    {
      bf16x8 qa[4];
#pragma unroll
      for (int mt = 0; mt < 4; ++mt) qa[mt] = *(const bf16x8*)(q_l + (mt * 16 + r) * 40 + g * 8);
#pragma unroll
      for (int nt = 0; nt < 4; ++nt) {
        bf16x8 kf = *(const bf16x8*)(k_l + (nt * 16 + r) * 40 + g * 8);
#pragma unroll
        for (int mt = 0; mt < 4; ++mt)
          sA[mt][nt] = __builtin_amdgcn_mfma_f32_16x16x32_bf16(qa[mt], kf, sA[mt][nt], 0, 0, 0);
      }
    }
    // ---- softmax (+rel-pos-bias +shift mask, both computed analytically) ----
#pragma unroll
    for (int mt = 0; mt < 4; ++mt) {
#pragma unroll
      for (int j = 0; j < 4; ++j) {
        const int it = mt * 16 + g * 4 + j;
        float v4[4];
#pragma unroll
        for (int nt = 0; nt < 4; ++nt) {
          const int jt = nt * 16 + r;
          float sv = sA[mt][nt][j];
          if (jt >= 49) {
            sv = -1e30f;
          } else if (it < 49) {
            int yi = it / 7, xi = it - yi * 7;
            int yj = jt / 7, xj = jt - yj * 7;
            sv += rpb[((yi - yj + 6) * 13 + (xi - xj + 6)) * 12 + head];
            int hi = (widx >> 3) * 7 + yi, wi2 = (widx & 7) * 7 + xi;
            int hj = (widx >> 3) * 7 + yj, wj2 = (widx & 7) * 7 + xj;
            int ri = (hi < 49 ? 0 : (hi < 53 ? 1 : 2)) * 3 + (wi2 < 49 ? 0 : (wi2 < 53 ? 1 : 2));
            int rj = (hj < 49 ? 0 : (hj < 53 ? 1 : 2)) * 3 + (wj2 < 49 ? 0 : (wj2 < 53 ? 1 : 2));
            if (ri != rj) sv -= 100.f;
          }
          v4[nt] = sv;
        }
        float mx = fmaxf(fmaxf(v4[0], v4[1]), fmaxf(v4[2], v4[3]));
#pragma unroll
        for (int m = 1; m < 16; m <<= 1) mx = fmaxf(mx, __shfl_xor(mx, m, 64));
        float sum = 0.f;
#pragma unroll
        for (int nt = 0; nt < 4; ++nt) { v4[nt] = __expf(v4[nt] - mx); sum += v4[nt]; }
#pragma unroll
        for (int m = 1; m < 16; m <<= 1) sum += __shfl_xor(sum, m, 64);
        float inv = 1.f / sum;
#pragma unroll
        for (int nt = 0; nt < 4; ++nt) sA[mt][nt][j] = v4[nt] * inv;
      }
    }
    __syncthreads();
#pragma unroll
    for (int mt = 0; mt < 4; ++mt)
#pragma unroll
      for (int nt = 0; nt < 4; ++nt)
#pragma unroll
        for (int j = 0; j < 4; ++j)
          P_l[(mt * 16 + g * 4 + j) * 72 + nt * 16 + r] = __float2bfloat16(sA[mt][nt][j]);
    __syncthreads();
    // ---- phase 3: out = P @ V ----
    f32x4 oA[4][2] = {};
#pragma unroll
    for (int ks = 0; ks < 2; ++ks) {
      bf16x8 pa[4];
#pragma unroll
      for (int mt = 0; mt < 4; ++mt)
        pa[mt] = *(const bf16x8*)(P_l + (mt * 16 + r) * 72 + ks * 32 + g * 8);
#pragma unroll
      for (int nt = 0; nt < 2; ++nt) {
        bf16x8 vb = *(const bf16x8*)(vT + (nt * 16 + r) * 72 + ks * 32 + g * 8);
#pragma unroll
        for (int mt = 0; mt < 4; ++mt)
          oA[mt][nt] = __builtin_amdgcn_mfma_f32_16x16x32_bf16(pa[mt], vb, oA[mt][nt], 0, 0, 0);
      }
    }
#pragma unroll
    for (int mt = 0; mt < 4; ++mt)
#pragma unroll
      for (int nt = 0; nt < 2; ++nt)
#pragma unroll
        for (int j = 0; j < 4; ++j) {
          int row = mt * 16 + g * 4 + j;
          if (row < 49)
            ao[((size_t)win * 49 + row) * 384 + head * 32 + nt * 16 + r] =
                __float2bfloat16(oA[mt][nt][j]);
        }
    __syncthreads();
  }
}

// ---------- generic MFMA GEMM: out[M x N] = A[M x KD] @ W^T, fused epilogues ----------
enum { EPI_PROJ = 0, EPI_SE1 = 1, EPI_SE2 = 2, EPI_C1 = 3, EPI_C2 = 4 };

template <int EPI, int KD, int NT, bool AF32>
__global__ __launch_bounds__(256) void gemm_k(const void* Ap, const __hip_bfloat16* __restrict__ W,
                                              const float* __restrict__ bias, const float* p0,
                                              const float* p1, const float* p2, void* outp) {
  const int lane = threadIdx.x & 63;
  const int wave = threadIdx.x >> 6;
  const int g = lane >> 4, r = lane & 15;
  const int row0 = blockIdx.x * 64;
  const int n0 = wave * (NT * 16);

  f32x4 acc[NT][4] = {};

  for (int kk = 0; kk < KD / 32; ++kk) {
    const int kb = kk * 32 + g * 8;
    bf16x8 af[4];
    if constexpr (AF32) {
      const float* A = (const float*)Ap;
#pragma unroll
      for (int mt = 0; mt < 4; ++mt) {
        const float4* s = (const float4*)(A + (size_t)(row0 + mt * 16 + r) * KD + kb);
        float4 a = s[0], b = s[1];
        bf16x8 t;
        t[0] = tobf(a.x); t[1] = tobf(a.y); t[2] = tobf(a.z); t[3] = tobf(a.w);
        t[4] = tobf(b.x); t[5] = tobf(b.y); t[6] = tobf(b.z); t[7] = tobf(b.w);
        af[mt] = t;
      }
    } else {
      const __hip_bfloat16* A = (const __hip_bfloat16*)Ap;
#pragma unroll
      for (int mt = 0; mt < 4; ++mt)
        af[mt] = *(const bf16x8*)(A + (size_t)(row0 + mt * 16 + r) * KD + kb);
    }
#pragma unroll
    for (int nt = 0; nt < NT; ++nt) {
      bf16x8 bf = *(const bf16x8*)(W + (size_t)(n0 + nt * 16 + r) * KD + kb);
#pragma unroll
      for (int mt = 0; mt < 4; ++mt)
        acc[nt][mt] = __builtin_amdgcn_mfma_f32_16x16x32_bf16(af[mt], bf, acc[nt][mt], 0, 0, 0);
    }
  }

#pragma unroll
  for (int mt = 0; mt < 4; ++mt) {
#pragma unroll
    for (int j = 0; j < 4; ++j) {
      const int row = row0 + mt * 16 + g * 4 + j;
      size_t obase;
      if constexpr (EPI == EPI_PROJ) {
        int wi = row / 49, n = row - wi * 49;
        int b = wi >> 6, widx = wi & 63;
        int n7 = n / 7;
        int hp = (widx >> 3) * 7 + n7, wp = (widx & 7) * 7 + (n - n7 * 7);
        int ii = hp + 3; if (ii >= 56) ii -= 56;
        int jj = wp + 3; if (jj >= 56) jj -= 56;
        obase = ((size_t)b * 3136 + ii * 56 + jj) * 384;
      } else {
        obase = (size_t)row * (EPI == EPI_SE1 ? 192 : 384);
      }
#pragma unroll
      for (int nt = 0; nt < NT; ++nt) {
        const int col = n0 + nt * 16 + r;
        float v = acc[nt][mt][j] + bias[col];
        if constexpr (EPI == EPI_PROJ) {
          ((float*)outp)[obase + col] = p0[obase + col] + v;  // residual add (shortcut x)
        } else if constexpr (EPI == EPI_SE1) {
          ((__hip_bfloat16*)outp)[obase + col] = __float2bfloat16(fmaxf(v, 0.f));
        } else if constexpr (EPI == EPI_SE2) {
          float gate = 1.f / (1.f + __expf(-v));
          ((float*)outp)[obase + col] = p0[obase + col] * gate;  // x2 = x1*sigmoid (in-place ok)
        } else if constexpr (EPI == EPI_C1) {
          float gl = 0.5f * v * (1.f + erff(v * 0.70710678118654752f));
          ((__hip_bfloat16*)outp)[obase + col] = __float2bfloat16(gl * p0[col] + p1[col]);
        } else {  // EPI_C2
          float y = v * p0[col] + p1[col];
          ((float*)outp)[obase + col] = p2[obase + col] + y;  // final = x2 + y (in-place ok)
        }
      }
    }
  }
}

// ---------- depthwise 3x3 (NHWC, 8 ch per thread) + gelu*bn2 ----------
__global__ __launch_bounds__(256) void dw_kernel(const __hip_bfloat16* __restrict__ y1,
                                                 const float* __restrict__ w,
                                                 const float* __restrict__ wb,
                                                 const float* __restrict__ g2,
                                                 const float* __restrict__ b2,
                                                 __hip_bfloat16* __restrict__ y2) {
  int tid = blockIdx.x * 256 + threadIdx.x;
  const int c8 = tid % 48;
  int t = tid / 48;  // b*3136 + h*56 + w
  const int wq = t % 56;
  const int t2 = t / 56;
  const int hq = t2 % 56;
  const int b = t2 / 56;
  const int cb = c8 * 8;
  float acc[8];
#pragma unroll
  for (int i = 0; i < 8; ++i) acc[i] = wb[cb + i];
#pragma unroll
  for (int ky = 0; ky < 3; ++ky) {
    int hh = hq + ky - 1;
    if ((unsigned)hh >= 56u) continue;
#pragma unroll
    for (int kx = 0; kx < 3; ++kx) {
      int wwp = wq + kx - 1;
      if ((unsigned)wwp >= 56u) continue;
      u16x8 vv = *(const u16x8*)(y1 + ((size_t)(b * 3136 + hh * 56 + wwp)) * 384 + cb);
#pragma unroll
      for (int i = 0; i < 8; ++i) {
        float f = __uint_as_float((unsigned)vv[i] << 16);
        acc[i] += f * w[(cb + i) * 9 + ky * 3 + kx];
      }
    }
  }
  u16x8 o;
#pragma unroll
  for (int i = 0; i < 8; ++i) {
    float u = acc[i];
    float gl = 0.5f * u * (1.f + erff(u * 0.70710678118654752f));
    o[i] = f2u(gl * g2[cb + i] + b2[cb + i]);
  }
  *(u16x8*)(y2 + ((size_t)t) * 384 + cb) = o;
}

extern "C" void kernel_launch(void* const* d_in, const int* in_sizes, int n_in, void* d_out,
                              int out_size, void* d_ws, size_t ws_size, hipStream_t stream) {
  (void)in_sizes; (void)n_in; (void)out_size; (void)ws_size;
  const float* x = (const float*)d_in[0];
  const float* n1g = (const float*)d_in[1];
  const float* n1b = (const float*)d_in[2];
  const float* qkv_w = (const float*)d_in[3];
  const float* qkv_b = (const float*)d_in[4];
  const float* rpb = (const float*)d_in[5];
  const float* proj_w = (const float*)d_in[6];
  const float* proj_b = (const float*)d_in[7];
  const float* se1_w = (const float*)d_in[8];
  const float* se1_b = (const float*)d_in[9];
  const float* se2_w = (const float*)d_in[10];
  const float* se2_b = (const float*)d_in[11];
  const float* n2g = (const float*)d_in[12];
  const float* n2b = (const float*)d_in[13];
  const float* c1_w = (const float*)d_in[14];
  const float* c1_b = (const float*)d_in[15];
  const float* bn1g = (const float*)d_in[16];
  const float* bn1b = (const float*)d_in[17];
  const float* dw_w = (const float*)d_in[18];
  const float* dw_b = (const float*)d_in[19];
  const float* bn2g = (const float*)d_in[20];
  const float* bn2b = (const float*)d_in[21];
  const float* c2_w = (const float*)d_in[22];
  const float* c2_b = (const float*)d_in[23];
  const float* bn3g = (const float*)d_in[24];
  const float* bn3b = (const float*)d_in[25];

  char* ws = (char*)d_ws;
  __hip_bfloat16* xn = (__hip_bfloat16*)(ws + OFF_XN);
  __hip_bfloat16* ao = (__hip_bfloat16*)(ws + OFF_AO);
  __hip_bfloat16* wbp = (__hip_bfloat16*)(ws + OFF_WB);
  __hip_bfloat16* qkv_wb = wbp;             // 442368
  __hip_bfloat16* proj_wb = wbp + 442368;   // 147456
  __hip_bfloat16* se1_wb = wbp + 589824;    // 73728
  __hip_bfloat16* se2_wb = wbp + 663552;    // 73728
  __hip_bfloat16* c1_wb = wbp + 737280;     // 147456
  __hip_bfloat16* c2_wb = wbp + 884736;     // 147456
  float* out = (float*)d_out;

  cvt_kernel<<<1728, 256, 0, stream>>>(qkv_w, qkv_wb, 442368);
  cvt_kernel<<<576, 256, 0, stream>>>(proj_w, proj_wb, 147456);
  cvt_kernel<<<288, 256, 0, stream>>>(se1_w, se1_wb, 73728);
  cvt_kernel<<<288, 256, 0, stream>>>(se2_w, se2_wb, 73728);
  cvt_kernel<<<576, 256, 0, stream>>>(c1_w, c1_wb, 147456);
  cvt_kernel<<<576, 256, 0, stream>>>(c2_w, c2_wb, 147456);

  // LN1 + shift + window partition -> xn (bf16, windowed)
  ln_kernel<true><<<25088, 256, 0, stream>>>(x, n1g, n1b, xn);
  // fused window attention -> ao (bf16, windowed)
  attn_kernel<<<2048, 256, 0, stream>>>(xn, qkv_wb, qkv_b, rpb, ao);
  // proj + window-reverse + roll-back + residual -> x1 (fp32, in d_out)
  gemm_k<EPI_PROJ, 384, 6, false><<<1568, 256, 0, stream>>>(ao, proj_wb, proj_b, x, nullptr,
                                                            nullptr, out);
  // SE: g1 = relu(x1 @ se1^T) -> ao (bf16 [M][192])
  gemm_k<EPI_SE1, 384, 3, true><<<1568, 256, 0, stream>>>(out, se1_wb, se1_b, nullptr, nullptr,
                                                          nullptr, ao);
  // x2 = x1 * sigmoid(g1 @ se2^T) -> d_out (in place)
  gemm_k<EPI_SE2, 192, 6, false><<<1568, 256, 0, stream>>>(ao, se2_wb, se2_b, out, nullptr,
                                                           nullptr, out);
  // LN2 -> xn (bf16, plain token order)
  ln_kernel<false><<<25088, 256, 0, stream>>>(out, n2g, n2b, xn);
  // y1 = gelu(xn @ c1^T)*bn1 -> ao
  gemm_k<EPI_C1, 384, 6, false><<<1568, 256, 0, stream>>>(xn, c1_wb, c1_b, bn1g, bn1b, nullptr,
                                                          ao);
  // y2 = gelu(dwconv(y1))*bn2 -> xn
  dw_kernel<<<18816, 256, 0, stream>>>(ao, dw_w, dw_b, bn2g, bn2b, xn);
  // out = x2 + (y2 @ c2^T)*bn3 -> d_out (in place)
  gemm_k<EPI_C2, 384, 6, false><<<1568, 256, 0, stream>>>(xn, c2_wb, c2_b, bn3g, bn3b, out, out);
}

// Round 2
// 1987.069 us; speedup vs baseline: 1.3275x; 1.3275x over previous
//
#include <hip/hip_runtime.h>
#include <hip/hip_bf16.h>

typedef __attribute__((ext_vector_type(4))) float f32x4;
typedef __attribute__((ext_vector_type(8))) __bf16 bf16x8;
typedef __attribute__((ext_vector_type(8))) unsigned short u16x8;

#define SCALE_ 0.17677669529663687f  /* 32^-0.5 */

// ---------- workspace layout (bytes) ----------
#define OFF_XN 0ull                  // bf16 [100352][384]  (windowed LN1 out; later y2)
#define OFF_AO 77070336ull           // bf16 [100352][384]  (attn out; later g1, y1)
#define OFF_WB 154140672ull          // bf16 weight copies (1,032,192 elems)
#define OFF_WT 156205056ull          // f32 [9][384] repacked dw weights (13824 B)

__device__ __forceinline__ __bf16 tobf(float f) {
  __hip_bfloat16 h = __float2bfloat16(f);
  return __builtin_bit_cast(__bf16, h);
}
__device__ __forceinline__ unsigned short f2u(float f) {
  return __builtin_bit_cast(unsigned short, __float2bfloat16(f));
}

// ---------- fp32 -> bf16 weight copy ----------
__global__ __launch_bounds__(256) void cvt_kernel(const float* __restrict__ src,
                                                  __hip_bfloat16* __restrict__ dst, int n) {
  int i = blockIdx.x * 256 + threadIdx.x;
  int stride = gridDim.x * 256;
  for (; i < n; i += stride) dst[i] = __float2bfloat16(src[i]);
}

// ---------- repack dw weights [384][9] -> [9][384] ----------
__global__ __launch_bounds__(256) void dwrep_kernel(const float* __restrict__ src,
                                                    float* __restrict__ dst) {
  int i = blockIdx.x * 256 + threadIdx.x;
  if (i < 3456) {
    int c = i / 9, k = i - c * 9;
    dst[k * 384 + c] = src[i];
  }
}

// ---------- LayerNorm (one wave per token); WIN: write to rolled+windowed position ----------
template <bool WIN>
__global__ __launch_bounds__(256) void ln_kernel(const float* __restrict__ x,
                                                 const float* __restrict__ gm,
                                                 const float* __restrict__ bt,
                                                 __hip_bfloat16* __restrict__ out) {
  const int tok = blockIdx.x * 4 + (threadIdx.x >> 6);
  const int lane = threadIdx.x & 63;
  const float2* row = (const float2*)(x + (size_t)tok * 384);
  float2 v[3];
  v[0] = row[lane]; v[1] = row[lane + 64]; v[2] = row[lane + 128];
  float s = 0.f, sq = 0.f;
#pragma unroll
  for (int i = 0; i < 3; ++i) { s += v[i].x + v[i].y; sq += v[i].x * v[i].x + v[i].y * v[i].y; }
#pragma unroll
  for (int m = 1; m < 64; m <<= 1) { s += __shfl_xor(s, m, 64); sq += __shfl_xor(sq, m, 64); }
  const float mean = s * (1.f / 384.f);
  const float var = sq * (1.f / 384.f) - mean * mean;
  const float rstd = rsqrtf(var + 1e-5f);
  size_t dst;
  if constexpr (WIN) {
    int b = tok / 3136, l = tok - b * 3136;
    int i = l / 56, j = l - i * 56;
    int hp = i - 3; if (hp < 0) hp += 56;
    int wp = j - 3; if (wp < 0) wp += 56;
    int wi = (hp / 7) * 8 + wp / 7;
    int n = (hp % 7) * 7 + wp % 7;
    dst = (size_t)(b * 64 + wi) * 49 + n;
  } else {
    dst = (size_t)tok;
  }
  unsigned int* o = (unsigned int*)(out + dst * 384);
  const float2* G = (const float2*)gm;
  const float2* Bv = (const float2*)bt;
#pragma unroll
  for (int i = 0; i < 3; ++i) {
    int j = lane + 64 * i;
    float2 gv = G[j], bv = Bv[j];
    float a = (v[i].x - mean) * rstd * gv.x + bv.x;
    float b2 = (v[i].y - mean) * rstd * gv.y + bv.y;
    o[j] = (unsigned)f2u(a) | ((unsigned)f2u(b2) << 16);
  }
}

// ---------- fused window attention: one block per window, one wave = 3 heads ----------
__global__ __launch_bounds__(256) void attn_kernel(const __hip_bfloat16* __restrict__ xn,
                                                   const __hip_bfloat16* __restrict__ wq,
                                                   const float* __restrict__ qb,
                                                   const float* __restrict__ rpb,
                                                   __hip_bfloat16* __restrict__ ao) {
  const int win = blockIdx.x;        // 0..2047
  const int widx = win & 63;         // window-in-image
  const int lane = threadIdx.x & 63, wave = threadIdx.x >> 6;
  const int g = lane >> 4, r = lane & 15;

  __shared__ __align__(16) char lds_all[4][16384];
  // per-wave: q [64][40] @0 (5120B), k [64][40] @5120, vT [32][72] @10240 (4608B)
  // P [64][72] overlays q+k (9216B <= 10240B)
  __hip_bfloat16* q_l = (__hip_bfloat16*)&lds_all[wave][0];
  __hip_bfloat16* k_l = (__hip_bfloat16*)&lds_all[wave][5120];
  __hip_bfloat16* vT = (__hip_bfloat16*)&lds_all[wave][10240];
  __hip_bfloat16* P_l = (__hip_bfloat16*)&lds_all[wave][0];

  bf16x8 zf;
#pragma unroll
  for (int i = 0; i < 8; ++i) zf[i] = tobf(0.f);

  for (int hh = 0; hh < 3; ++hh) {
    const int head = hh * 4 + wave;
    {
      // ---- phase 1: qkv = win @ Wqkv^T ----
      f32x4 acc[3][4][2] = {};
      for (int kk = 0; kk < 12; ++kk) {
        const int kb = kk * 32 + g * 8;
        bf16x8 af[4];
#pragma unroll
        for (int mt = 0; mt < 4; ++mt) {
          int t = mt * 16 + r;
          af[mt] = (t < 49) ? *(const bf16x8*)(xn + ((size_t)win * 49 + t) * 384 + kb) : zf;
        }
#pragma unroll
        for (int s = 0; s < 3; ++s) {
          const int ob = s * 384 + head * 32;
#pragma unroll
          for (int nt = 0; nt < 2; ++nt) {
            bf16x8 bf = *(const bf16x8*)(wq + (size_t)(ob + nt * 16 + r) * 384 + kb);
#pragma unroll
            for (int mt = 0; mt < 4; ++mt)
              acc[s][mt][nt] =
                  __builtin_amdgcn_mfma_f32_16x16x32_bf16(af[mt], bf, acc[s][mt][nt], 0, 0, 0);
          }
        }
      }
#pragma unroll
      for (int mt = 0; mt < 4; ++mt)
#pragma unroll
        for (int nt = 0; nt < 2; ++nt)
#pragma unroll
          for (int j = 0; j < 4; ++j) {
            int row = mt * 16 + g * 4 + j;
            int col = nt * 16 + r;
            float qv = (acc[0][mt][nt][j] + qb[head * 32 + col]) * SCALE_;
            float kv = acc[1][mt][nt][j] + qb[384 + head * 32 + col];
            float vv = acc[2][mt][nt][j] + qb[768 + head * 32 + col];
            q_l[row * 40 + col] = __float2bfloat16(qv);
            k_l[row * 40 + col] = __float2bfloat16(kv);
            vT[col * 72 + row] = __float2bfloat16(vv);
          }
    }
    __syncthreads();
    // ---- phase 2: S = q @ k^T (K=32, one mfma per tile) ----
    f32x4 sA[4][4] = {};
    {
      bf16x8 qa[4];
#pragma unroll
      for (int mt = 0; mt < 4; ++mt) qa[mt] = *(const bf16x8*)(q_l + (mt * 16 + r) * 40 + g * 8);
#pragma unroll
      for (int nt = 0; nt < 4; ++nt) {
        bf16x8 kf = *(const bf16x8*)(k_l + (nt * 16 + r) * 40 + g * 8);
#pragma unroll
        for (int mt = 0; mt < 4; ++mt)
          sA[mt][nt] = __builtin_amdgcn_mfma_f32_16x16x32_bf16(qa[mt], kf, sA[mt][nt], 0, 0, 0);
      }
    }
    // ---- softmax (+rel-pos-bias +shift mask, both computed analytically) ----
#pragma unroll
    for (int mt = 0; mt < 4; ++mt) {
#pragma unroll
      for (int j = 0; j < 4; ++j) {
        const int it = mt * 16 + g * 4 + j;
        float v4[4];
#pragma unroll
        for (int nt = 0; nt < 4; ++nt) {
          const int jt = nt * 16 + r;
          float sv = sA[mt][nt][j];
          if (jt >= 49) {
            sv = -1e30f;
          } else if (it < 49) {
            int yi = it / 7, xi = it - yi * 7;
            int yj = jt / 7, xj = jt - yj * 7;
            sv += rpb[((yi - yj + 6) * 13 + (xi - xj + 6)) * 12 + head];
            int hi = (widx >> 3) * 7 + yi, wi2 = (widx & 7) * 7 + xi;
            int hj = (widx >> 3) * 7 + yj, wj2 = (widx & 7) * 7 + xj;
            int ri = (hi < 49 ? 0 : (hi < 53 ? 1 : 2)) * 3 + (wi2 < 49 ? 0 : (wi2 < 53 ? 1 : 2));
            int rj = (hj < 49 ? 0 : (hj < 53 ? 1 : 2)) * 3 + (wj2 < 49 ? 0 : (wj2 < 53 ? 1 : 2));
            if (ri != rj) sv -= 100.f;
          }
          v4[nt] = sv;
        }
        float mx = fmaxf(fmaxf(v4[0], v4[1]), fmaxf(v4[2], v4[3]));
#pragma unroll
        for (int m = 1; m < 16; m <<= 1) mx = fmaxf(mx, __shfl_xor(mx, m, 64));
        float sum = 0.f;
#pragma unroll
        for (int nt = 0; nt < 4; ++nt) { v4[nt] = __expf(v4[nt] - mx); sum += v4[nt]; }
#pragma unroll
        for (int m = 1; m < 16; m <<= 1) sum += __shfl_xor(sum, m, 64);
        float inv = 1.f / sum;
#pragma unroll
        for (int nt = 0; nt < 4; ++nt) sA[mt][nt][j] = v4[nt] * inv;
      }
    }
    __syncthreads();
#pragma unroll
    for (int mt = 0; mt < 4; ++mt)
#pragma unroll
      for (int nt = 0; nt < 4; ++nt)
#pragma unroll
        for (int j = 0; j < 4; ++j)
          P_l[(mt * 16 + g * 4 + j) * 72 + nt * 16 + r] = __float2bfloat16(sA[mt][nt][j]);
    __syncthreads();
    // ---- phase 3: out = P @ V ----
    f32x4 oA[4][2] = {};
#pragma unroll
    for (int ks = 0; ks < 2; ++ks) {
      bf16x8 pa[4];
#pragma unroll
      for (int mt = 0; mt < 4; ++mt)
        pa[mt] = *(const bf16x8*)(P_l + (mt * 16 + r) * 72 + ks * 32 + g * 8);
#pragma unroll
      for (int nt = 0; nt < 2; ++nt) {
        bf16x8 vb = *(const bf16x8*)(vT + (nt * 16 + r) * 72 + ks * 32 + g * 8);
#pragma unroll
        for (int mt = 0; mt < 4; ++mt)
          oA[mt][nt] = __builtin_amdgcn_mfma_f32_16x16x32_bf16(pa[mt], vb, oA[mt][nt], 0, 0, 0);
      }
    }
#pragma unroll
    for (int mt = 0; mt < 4; ++mt)
#pragma unroll
      for (int nt = 0; nt < 2; ++nt)
#pragma unroll
        for (int j = 0; j < 4; ++j) {
          int row = mt * 16 + g * 4 + j;
          if (row < 49)
            ao[((size_t)win * 49 + row) * 384 + head * 32 + nt * 16 + r] =
                __float2bfloat16(oA[mt][nt][j]);
        }
    __syncthreads();
  }
}

// ---------- generic MFMA GEMM: out[M x N] = A[M x KD] @ W^T, fused epilogues ----------
enum { EPI_PROJ = 0, EPI_SE1 = 1, EPI_SE2 = 2, EPI_C1 = 3, EPI_C2 = 4 };

template <int EPI, int KD, int NT, bool AF32>
__global__ __launch_bounds__(256) void gemm_k(const void* Ap, const __hip_bfloat16* __restrict__ W,
                                              const float* __restrict__ bias, const float* p0,
                                              const float* p1, const float* p2, void* outp) {
  const int lane = threadIdx.x & 63;
  const int wave = threadIdx.x >> 6;
  const int g = lane >> 4, r = lane & 15;
  const int row0 = blockIdx.x * 64;
  const int n0 = wave * (NT * 16);

  f32x4 acc[NT][4] = {};

  for (int kk = 0; kk < KD / 32; ++kk) {
    const int kb = kk * 32 + g * 8;
    bf16x8 af[4];
    if constexpr (AF32) {
      const float* A = (const float*)Ap;
#pragma unroll
      for (int mt = 0; mt < 4; ++mt) {
        const float4* s = (const float4*)(A + (size_t)(row0 + mt * 16 + r) * KD + kb);
        float4 a = s[0], b = s[1];
        bf16x8 t;
        t[0] = tobf(a.x); t[1] = tobf(a.y); t[2] = tobf(a.z); t[3] = tobf(a.w);
        t[4] = tobf(b.x); t[5] = tobf(b.y); t[6] = tobf(b.z); t[7] = tobf(b.w);
        af[mt] = t;
      }
    } else {
      const __hip_bfloat16* A = (const __hip_bfloat16*)Ap;
#pragma unroll
      for (int mt = 0; mt < 4; ++mt)
        af[mt] = *(const bf16x8*)(A + (size_t)(row0 + mt * 16 + r) * KD + kb);
    }
#pragma unroll
    for (int nt = 0; nt < NT; ++nt) {
      bf16x8 bf = *(const bf16x8*)(W + (size_t)(n0 + nt * 16 + r) * KD + kb);
#pragma unroll
      for (int mt = 0; mt < 4; ++mt)
        acc[nt][mt] = __builtin_amdgcn_mfma_f32_16x16x32_bf16(af[mt], bf, acc[nt][mt], 0, 0, 0);
    }
  }

#pragma unroll
  for (int mt = 0; mt < 4; ++mt) {
#pragma unroll
    for (int j = 0; j < 4; ++j) {
      const int row = row0 + mt * 16 + g * 4 + j;
      size_t obase;
      if constexpr (EPI == EPI_PROJ) {
        int wi = row / 49, n = row - wi * 49;
        int b = wi >> 6, widx = wi & 63;
        int n7 = n / 7;
        int hp = (widx >> 3) * 7 + n7, wp = (widx & 7) * 7 + (n - n7 * 7);
        int ii = hp + 3; if (ii >= 56) ii -= 56;
        int jj = wp + 3; if (jj >= 56) jj -= 56;
        obase = ((size_t)b * 3136 + ii * 56 + jj) * 384;
      } else {
        obase = (size_t)row * (EPI == EPI_SE1 ? 192 : 384);
      }
#pragma unroll
      for (int nt = 0; nt < NT; ++nt) {
        const int col = n0 + nt * 16 + r;
        float v = acc[nt][mt][j] + bias[col];
        if constexpr (EPI == EPI_PROJ) {
          ((float*)outp)[obase + col] = p0[obase + col] + v;  // residual add (shortcut x)
        } else if constexpr (EPI == EPI_SE1) {
          ((__hip_bfloat16*)outp)[obase + col] = __float2bfloat16(fmaxf(v, 0.f));
        } else if constexpr (EPI == EPI_SE2) {
          float gate = 1.f / (1.f + __expf(-v));
          ((float*)outp)[obase + col] = p0[obase + col] * gate;  // x2 = x1*sigmoid (in-place ok)
        } else if constexpr (EPI == EPI_C1) {
          float gl = 0.5f * v * (1.f + erff(v * 0.70710678118654752f));
          ((__hip_bfloat16*)outp)[obase + col] = __float2bfloat16(gl * p0[col] + p1[col]);
        } else {  // EPI_C2
          float y = v * p0[col] + p1[col];
          ((float*)outp)[obase + col] = p2[obase + col] + y;  // final = x2 + y (in-place ok)
        }
      }
    }
  }
}

// ---------- depthwise 3x3 (NHWC) + gelu*bn2 — register sliding window, 14 outputs/thread ----------
__global__ __launch_bounds__(256) void dw_kernel(const __hip_bfloat16* __restrict__ y1,
                                                 const float* __restrict__ wt,  // [9][384]
                                                 const float* __restrict__ wb,
                                                 const float* __restrict__ g2,
                                                 const float* __restrict__ b2,
                                                 __hip_bfloat16* __restrict__ y2) {
  const int tid = blockIdx.x * 256 + threadIdx.x;  // 32*56*4*48 = 344064
  const int c8 = tid % 48;
  int t = tid / 48;
  const int q = t & 3; t >>= 2;
  const int hq = t % 56;
  const int b = t / 56;
  const int cb = c8 * 8;
  const int x0 = q * 14;

  float wr[9][8];
#pragma unroll
  for (int k = 0; k < 9; ++k) {
    float4 a = *(const float4*)(wt + k * 384 + cb);
    float4 c = *(const float4*)(wt + k * 384 + cb + 4);
    wr[k][0] = a.x; wr[k][1] = a.y; wr[k][2] = a.z; wr[k][3] = a.w;
    wr[k][4] = c.x; wr[k][5] = c.y; wr[k][6] = c.z; wr[k][7] = c.w;
  }
  // 'SAME' padding: zero the taps of out-of-range rows instead of branching per load
  if (hq == 0) {
#pragma unroll
    for (int k = 0; k < 3; ++k)
#pragma unroll
      for (int i = 0; i < 8; ++i) wr[k][i] = 0.f;
  }
  if (hq == 55) {
#pragma unroll
    for (int k = 6; k < 9; ++k)
#pragma unroll
      for (int i = 0; i < 8; ++i) wr[k][i] = 0.f;
  }
  float bias[8], gv[8], bv[8];
  {
    float4 a = *(const float4*)(wb + cb), c = *(const float4*)(wb + cb + 4);
    bias[0] = a.x; bias[1] = a.y; bias[2] = a.z; bias[3] = a.w;
    bias[4] = c.x; bias[5] = c.y; bias[6] = c.z; bias[7] = c.w;
    float4 d = *(const float4*)(g2 + cb), e = *(const float4*)(g2 + cb + 4);
    gv[0] = d.x; gv[1] = d.y; gv[2] = d.z; gv[3] = d.w;
    gv[4] = e.x; gv[5] = e.y; gv[6] = e.z; gv[7] = e.w;
    float4 f = *(const float4*)(b2 + cb), h = *(const float4*)(b2 + cb + 4);
    bv[0] = f.x; bv[1] = f.y; bv[2] = f.z; bv[3] = f.w;
    bv[4] = h.x; bv[5] = h.y; bv[6] = h.z; bv[7] = h.w;
  }
  const int hm = hq > 0 ? hq - 1 : 0;
  const int hp = hq < 55 ? hq + 1 : 55;
  const __hip_bfloat16* r0 = y1 + ((size_t)(b * 3136 + hm * 56)) * 384 + cb;
  const __hip_bfloat16* r1 = y1 + ((size_t)(b * 3136 + hq * 56)) * 384 + cb;
  const __hip_bfloat16* r2 = y1 + ((size_t)(b * 3136 + hp * 56)) * 384 + cb;
  __hip_bfloat16* op = y2 + ((size_t)(b * 3136 + hq * 56)) * 384 + cb;

  u16x8 zv;
#pragma unroll
  for (int i = 0; i < 8; ++i) zv[i] = 0;
#define LDC(rp, x) (((unsigned)(x) < 56u) ? *(const u16x8*)((rp) + (size_t)(x) * 384) : zv)

  u16x8 L0 = LDC(r0, x0 - 1), L1 = LDC(r1, x0 - 1), L2 = LDC(r2, x0 - 1);
  u16x8 C0 = LDC(r0, x0), C1 = LDC(r1, x0), C2 = LDC(r2, x0);
#pragma unroll
  for (int xi = 0; xi < 14; ++xi) {
    const int x = x0 + xi;
    u16x8 R0 = LDC(r0, x + 1), R1 = LDC(r1, x + 1), R2 = LDC(r2, x + 1);
    float acc[8];
#pragma unroll
    for (int i = 0; i < 8; ++i) acc[i] = bias[i];
#pragma unroll
    for (int i = 0; i < 8; ++i) {
      acc[i] += __uint_as_float((unsigned)L0[i] << 16) * wr[0][i];
      acc[i] += __uint_as_float((unsigned)C0[i] << 16) * wr[1][i];
      acc[i] += __uint_as_float((unsigned)R0[i] << 16) * wr[2][i];
      acc[i] += __uint_as_float((unsigned)L1[i] << 16) * wr[3][i];
      acc[i] += __uint_as_float((unsigned)C1[i] << 16) * wr[4][i];
      acc[i] += __uint_as_float((unsigned)R1[i] << 16) * wr[5][i];
      acc[i] += __uint_as_float((unsigned)L2[i] << 16) * wr[6][i];
      acc[i] += __uint_as_float((unsigned)C2[i] << 16) * wr[7][i];
      acc[i] += __uint_as_float((unsigned)R2[i] << 16) * wr[8][i];
    }
    u16x8 o;
#pragma unroll
    for (int i = 0; i < 8; ++i) {
      float u = acc[i];
      float gl = 0.5f * u * (1.f + erff(u * 0.70710678118654752f));
      o[i] = f2u(gl * gv[i] + bv[i]);
    }
    *(u16x8*)(op + (size_t)x * 384) = o;
    L0 = C0; L1 = C1; L2 = C2;
    C0 = R0; C1 = R1; C2 = R2;
  }
#undef LDC
}

extern "C" void kernel_launch(void* const* d_in, const int* in_sizes, int n_in, void* d_out,
                              int out_size, void* d_ws, size_t ws_size, hipStream_t stream) {
  (void)in_sizes; (void)n_in; (void)out_size; (void)ws_size;
  const float* x = (const float*)d_in[0];
  const float* n1g = (const float*)d_in[1];
  const float* n1b = (const float*)d_in[2];
  const float* qkv_w = (const float*)d_in[3];
  const float* qkv_b = (const float*)d_in[4];
  const float* rpb = (const float*)d_in[5];
  const float* proj_w = (const float*)d_in[6];
  const float* proj_b = (const float*)d_in[7];
  const float* se1_w = (const float*)d_in[8];
  const float* se1_b = (const float*)d_in[9];
  const float* se2_w = (const float*)d_in[10];
  const float* se2_b = (const float*)d_in[11];
  const float* n2g = (const float*)d_in[12];
  const float* n2b = (const float*)d_in[13];
  const float* c1_w = (const float*)d_in[14];
  const float* c1_b = (const float*)d_in[15];
  const float* bn1g = (const float*)d_in[16];
  const float* bn1b = (const float*)d_in[17];
  const float* dw_w = (const float*)d_in[18];
  const float* dw_b = (const float*)d_in[19];
  const float* bn2g = (const float*)d_in[20];
  const float* bn2b = (const float*)d_in[21];
  const float* c2_w = (const float*)d_in[22];
  const float* c2_b = (const float*)d_in[23];
  const float* bn3g = (const float*)d_in[24];
  const float* bn3b = (const float*)d_in[25];

  char* ws = (char*)d_ws;
  __hip_bfloat16* xn = (__hip_bfloat16*)(ws + OFF_XN);
  __hip_bfloat16* ao = (__hip_bfloat16*)(ws + OFF_AO);
  __hip_bfloat16* wbp = (__hip_bfloat16*)(ws + OFF_WB);
  float* wt = (float*)(ws + OFF_WT);
  __hip_bfloat16* qkv_wb = wbp;             // 442368
  __hip_bfloat16* proj_wb = wbp + 442368;   // 147456
  __hip_bfloat16* se1_wb = wbp + 589824;    // 73728
  __hip_bfloat16* se2_wb = wbp + 663552;    // 73728
  __hip_bfloat16* c1_wb = wbp + 737280;     // 147456
  __hip_bfloat16* c2_wb = wbp + 884736;     // 147456
  float* out = (float*)d_out;

  cvt_kernel<<<1728, 256, 0, stream>>>(qkv_w, qkv_wb, 442368);
  cvt_kernel<<<576, 256, 0, stream>>>(proj_w, proj_wb, 147456);
  cvt_kernel<<<288, 256, 0, stream>>>(se1_w, se1_wb, 73728);
  cvt_kernel<<<288, 256, 0, stream>>>(se2_w, se2_wb, 73728);
  cvt_kernel<<<576, 256, 0, stream>>>(c1_w, c1_wb, 147456);
  cvt_kernel<<<576, 256, 0, stream>>>(c2_w, c2_wb, 147456);
  dwrep_kernel<<<14, 256, 0, stream>>>(dw_w, wt);

  // LN1 + shift + window partition -> xn (bf16, windowed)
  ln_kernel<true><<<25088, 256, 0, stream>>>(x, n1g, n1b, xn);
  // fused window attention -> ao (bf16, windowed)
  attn_kernel<<<2048, 256, 0, stream>>>(xn, qkv_wb, qkv_b, rpb, ao);
  // proj + window-reverse + roll-back + residual -> x1 (fp32, in d_out)
  gemm_k<EPI_PROJ, 384, 6, false><<<1568, 256, 0, stream>>>(ao, proj_wb, proj_b, x, nullptr,
                                                            nullptr, out);
  // SE: g1 = relu(x1 @ se1^T) -> ao (bf16 [M][192])
  gemm_k<EPI_SE1, 384, 3, true><<<1568, 256, 0, stream>>>(out, se1_wb, se1_b, nullptr, nullptr,
                                                          nullptr, ao);
  // x2 = x1 * sigmoid(g1 @ se2^T) -> d_out (in place)
  gemm_k<EPI_SE2, 192, 6, false><<<1568, 256, 0, stream>>>(ao, se2_wb, se2_b, out, nullptr,
                                                           nullptr, out);
  // LN2 -> xn (bf16, plain token order)
  ln_kernel<false><<<25088, 256, 0, stream>>>(out, n2g, n2b, xn);
  // y1 = gelu(xn @ c1^T)*bn1 -> ao
  gemm_k<EPI_C1, 384, 6, false><<<1568, 256, 0, stream>>>(xn, c1_wb, c1_b, bn1g, bn1b, nullptr,
                                                          ao);
  // y2 = gelu(dwconv(y1))*bn2 -> xn
  dw_kernel<<<1344, 256, 0, stream>>>(ao, wt, dw_b, bn2g, bn2b, xn);
  // out = x2 + (y2 @ c2^T)*bn3 -> d_out (in place)
  gemm_k<EPI_C2, 384, 6, false><<<1568, 256, 0, stream>>>(xn, c2_wb, c2_b, bn3g, bn3b, out, out);
}